// Round 4
// baseline (231.873 us; speedup 1.0000x reference)
//
#include <hip/hip_runtime.h>

#define B_ 64
#define T_ 512
#define D_ 768
#define K_ 21
#define NCHUNK 32    // chunks over t=1..511
#define CLEN 16      // steps per chunk
#define GSTRIDE 448  // padded 21*21
#define LOG21 3.0445224377234229965f

// ---------------- Kernel 1: logits[32768,21] = A[32768,768] @ W^T + b ----------
// 512 thr/block, 256 blocks (1/CU). lane -> (rid = tid/16, slice m = tid%16);
// thread owns 4 rows: rid + 32*r. The 21 W LDS reads per A-window amortize over
// 4 rows -> LDS instr /4 vs R3. A loads coalesced (16 lanes x 16B = 256B/row).
__global__ __launch_bounds__(512) void proj_kernel(
    const float* __restrict__ A,
    const float* __restrict__ W,
    const float* __restrict__ bias,
    float* __restrict__ out)            // d_out: [0]=loss, [1..]=logits
{
    __shared__ float Wl[K_ * D_];       // 63 KB
    const int tid = threadIdx.x;
    {
        const float4* Wg = (const float4*)W;
        float4* Ws = (float4*)Wl;
        for (int i = tid; i < K_ * D_ / 4; i += 512) Ws[i] = Wg[i];
    }
    __syncthreads();

    const int m = tid & 15;                        // col slice
    const int rid = tid >> 4;                      // 0..31
    const size_t row0 = (size_t)blockIdx.x * 128 + rid;   // rows row0 + 32*r
    const float4* __restrict__ Ar0 = (const float4*)(A + (row0      ) * D_);
    const float4* __restrict__ Ar1 = (const float4*)(A + (row0 + 32 ) * D_);
    const float4* __restrict__ Ar2 = (const float4*)(A + (row0 + 64 ) * D_);
    const float4* __restrict__ Ar3 = (const float4*)(A + (row0 + 96 ) * D_);
    const float4* __restrict__ Wl4 = (const float4*)Wl;

    float acc0[K_], acc1[K_], acc2[K_], acc3[K_];
    #pragma unroll
    for (int k = 0; k < K_; ++k) { acc0[k]=0.f; acc1[k]=0.f; acc2[k]=0.f; acc3[k]=0.f; }

    #pragma unroll 2
    for (int i = 0; i < 12; ++i) {
        const float4 a0 = Ar0[m + 16 * i];
        const float4 a1 = Ar1[m + 16 * i];
        const float4 a2 = Ar2[m + 16 * i];
        const float4 a3 = Ar3[m + 16 * i];
        #pragma unroll
        for (int k = 0; k < K_; ++k) {
            const float4 w = Wl4[k * 192 + m + 16 * i];
            acc0[k] = fmaf(a0.x, w.x, fmaf(a0.y, w.y, fmaf(a0.z, w.z, fmaf(a0.w, w.w, acc0[k]))));
            acc1[k] = fmaf(a1.x, w.x, fmaf(a1.y, w.y, fmaf(a1.z, w.z, fmaf(a1.w, w.w, acc1[k]))));
            acc2[k] = fmaf(a2.x, w.x, fmaf(a2.y, w.y, fmaf(a2.z, w.z, fmaf(a2.w, w.w, acc2[k]))));
            acc3[k] = fmaf(a3.x, w.x, fmaf(a3.y, w.y, fmaf(a3.z, w.z, fmaf(a3.w, w.w, acc3[k]))));
        }
    }

    // reduce over the 16 slice lanes (xor offsets stay within the group)
    #pragma unroll
    for (int k = 0; k < K_; ++k) {
        float v0 = acc0[k], v1 = acc1[k], v2 = acc2[k], v3 = acc3[k];
        v0 += __shfl_xor(v0, 1, 64); v1 += __shfl_xor(v1, 1, 64);
        v2 += __shfl_xor(v2, 1, 64); v3 += __shfl_xor(v3, 1, 64);
        v0 += __shfl_xor(v0, 2, 64); v1 += __shfl_xor(v1, 2, 64);
        v2 += __shfl_xor(v2, 2, 64); v3 += __shfl_xor(v3, 2, 64);
        v0 += __shfl_xor(v0, 4, 64); v1 += __shfl_xor(v1, 4, 64);
        v2 += __shfl_xor(v2, 4, 64); v3 += __shfl_xor(v3, 4, 64);
        v0 += __shfl_xor(v0, 8, 64); v1 += __shfl_xor(v1, 8, 64);
        v2 += __shfl_xor(v2, 8, 64); v3 += __shfl_xor(v3, 8, 64);
        acc0[k] = v0; acc1[k] = v1; acc2[k] = v2; acc3[k] = v3;
    }

    float* o0 = out + 1 + (row0      ) * K_;
    float* o1 = out + 1 + (row0 + 32 ) * K_;
    float* o2 = out + 1 + (row0 + 64 ) * K_;
    float* o3 = out + 1 + (row0 + 96 ) * K_;
    #pragma unroll
    for (int k = 0; k < K_; ++k) {
        if (m == (k & 15)) {
            const float bb = bias[k];
            o0[k] = acc0[k] + bb;
            o1[k] = acc1[k] + bb;
            o2[k] = acc2[k] + bb;
            o3[k] = acc3[k] + bb;
        }
    }
}

// ---------------- Kernel 2a: per-(batch,chunk) transfer-matrix product --------
// G_c = Prod_{t in chunk, mask=1} (ET * diag(em_t)) / 21^n, em normalized by
// per-step max. One wave per task; lane l<63 -> (row i = l/3, colgroup jg = l%3).
__global__ __launch_bounds__(64) void chunk_kernel(
    const float* __restrict__ outF,
    const int*   __restrict__ mask,
    const float* __restrict__ trans,
    float* __restrict__ G,
    float* __restrict__ SC)
{
    __shared__ float M0[441], M1[441];
    __shared__ float sET[441];
    __shared__ float em[CLEN * K_];
    __shared__ float smx[CLEN];
    __shared__ int   smask[CLEN];

    const int c = blockIdx.x;
    const int b = blockIdx.y;
    const int lane = threadIdx.x;
    const int t0 = c * CLEN + 1;
    const int nst = min(CLEN, T_ - t0);     // 16, except 15 for last chunk
    const int i_ = lane / 3;
    const int jg = lane - i_ * 3;
    const bool act = lane < 63;

    const float* lg = outF + 1 + (size_t)b * T_ * K_;
    for (int idx = lane; idx < nst * K_; idx += 64) em[idx] = lg[t0 * K_ + idx];
    if (lane < nst) smask[lane] = mask[b * T_ + t0 + lane];
    for (int idx = lane; idx < 441; idx += 64) {
        M0[idx] = (idx % 22 == 0) ? 1.0f : 0.0f;     // identity
        sET[idx] = __expf(trans[idx]);               // coalesced trans read
    }
    __syncthreads();

    if (lane < nst) {
        float mx = -1e30f;
        for (int j = 0; j < K_; ++j) mx = fmaxf(mx, em[lane * K_ + j]);
        smx[lane] = mx;
    }
    __syncthreads();
    for (int idx = lane; idx < nst * K_; idx += 64)
        em[idx] = __expf(em[idx] - smx[idx / K_]) * (1.0f / 21.0f);

    float ETc[K_ * 7];
    if (act) {
        #pragma unroll
        for (int mm = 0; mm < K_; ++mm) {
            #pragma unroll
            for (int q = 0; q < 7; ++q)
                ETc[mm * 7 + q] = sET[mm * K_ + jg * 7 + q];
        }
    }
    __syncthreads();

    int cur = 0;
    for (int s = 0; s < nst; ++s) {
        if (smask[s] != 0) {                 // wave-uniform
            const float* Mr = cur ? M1 : M0;
            float*       Mw = cur ? M0 : M1;
            float facc[7] = {0.f,0.f,0.f,0.f,0.f,0.f,0.f};
            if (act) {
                #pragma unroll
                for (int mm = 0; mm < K_; ++mm) {
                    const float lm = Mr[i_ * K_ + mm];
                    #pragma unroll
                    for (int q = 0; q < 7; ++q)
                        facc[q] = fmaf(lm, ETc[mm * 7 + q], facc[q]);
                }
            }
            __syncthreads();
            if (act) {
                #pragma unroll
                for (int q = 0; q < 7; ++q)
                    Mw[i_ * K_ + jg * 7 + q] = facc[q] * em[s * K_ + jg * 7 + q];
            }
            __syncthreads();
            cur ^= 1;
        }
    }

    float* Gc = G + (size_t)(b * NCHUNK + c) * GSTRIDE;
    const float* Mf = cur ? M1 : M0;
    for (int idx = lane; idx < 441; idx += 64) Gc[idx] = Mf[idx];
    if (lane == 0) {
        float sc = 0.0f;
        for (int s = 0; s < nst; ++s)
            if (smask[s] != 0) sc += smx[s] + LOG21;
        SC[b * NCHUNK + c] = sc;
    }
}

// ---------------- Kernel 2b: 32-step scan + gold score per batch ---------------
// Whole per-batch G (56 KB) staged into LDS upfront with deep load pipeline ->
// no per-iteration global latency in the scan loop.
__global__ __launch_bounds__(64) void scan_kernel(
    const float* __restrict__ outF,
    const int*   __restrict__ tags,
    const int*   __restrict__ mask,
    const float* __restrict__ trans,
    const float* __restrict__ startT,
    const float* __restrict__ endT,
    const float* __restrict__ G,
    const float* __restrict__ SC,
    float* __restrict__ ll,
    float* __restrict__ msum)
{
    __shared__ float sG[NCHUNK * GSTRIDE];   // 57344 B
    __shared__ float sv[24];
    __shared__ float sm[T_];
    __shared__ int   st[T_];
    const int b = blockIdx.x;
    const int lane = threadIdx.x;
    const int jc = min(lane, K_ - 1);
    const float* lg = outF + 1 + (size_t)b * T_ * K_;
    const float* Gb = G + (size_t)b * NCHUNK * GSTRIDE;

    // stage all 32 chunks (3584 float4, coalesced, 56/lane outstanding)
    {
        const float4* Gf4 = (const float4*)Gb;
        float4* dst = (float4*)sG;
        for (int j = lane; j < NCHUNK * GSTRIDE / 4; j += 64) dst[j] = Gf4[j];
    }
    for (int t = lane; t < T_; t += 64) {
        sm[t] = (float)mask[b * T_ + t];
        st[t] = tags[b * T_ + t];
    }
    const float scv = (lane < NCHUNK) ? SC[b * NCHUNK + lane] : 0.0f;

    // v0 = exp(start + emit0 - max)
    float val = (lane < K_) ? startT[lane] + lg[lane] : -1e30f;
    float mx = val;
    #pragma unroll
    for (int off = 32; off >= 1; off >>= 1) mx = fmaxf(mx, __shfl_xor(mx, off, 64));
    float v = (lane < K_) ? __expf(val - mx) : 0.0f;
    float C = mx;
    __syncthreads();

    for (int c = 0; c < NCHUNK; ++c) {
        if (lane < K_) sv[lane] = v;
        __syncthreads();
        const float* Gc = sG + c * GSTRIDE;
        float a0 = 0.f, a1 = 0.f, a2 = 0.f;
        #pragma unroll
        for (int i = 0; i < K_; i += 3) {
            a0 = fmaf(sv[i],     Gc[i * K_ + jc],       a0);
            a1 = fmaf(sv[i + 1], Gc[(i + 1) * K_ + jc], a1);
            a2 = fmaf(sv[i + 2], Gc[(i + 2) * K_ + jc], a2);
        }
        const float s = a0 + a1 + a2;
        C += __shfl(scv, c, 64);
        float m2 = (lane < K_) ? s : 0.0f;
        #pragma unroll
        for (int off = 32; off >= 1; off >>= 1) m2 = fmaxf(m2, __shfl_xor(m2, off, 64));
        v = (lane < K_) ? s / m2 : 0.0f;
        C += __logf(m2);
        __syncthreads();     // all lanes done with sv before next overwrite
    }

    float term = (lane < K_) ? v * __expf(endT[lane]) : 0.0f;
    #pragma unroll
    for (int off = 32; off >= 1; off >>= 1) term += __shfl_xor(term, off, 64);
    const float logZ = C + __logf(term);

    // gold-path score + mask sum
    float sc = 0.0f, ms = 0.0f;
    for (int t = lane; t < T_; t += 64) {
        const float mt = sm[t];
        ms += mt;
        if (t < T_ - 1) {
            const int ct = st[t], nt2 = st[t + 1];
            sc += trans[ct * K_ + nt2] * sm[t + 1] + lg[t * K_ + ct] * mt;
        }
    }
    #pragma unroll
    for (int off = 32; off >= 1; off >>= 1) {
        sc += __shfl_xor(sc, off, 64);
        ms += __shfl_xor(ms, off, 64);
    }
    if (lane == 0) {
        const int lastIdx = (int)ms - 1;
        const int lastTag = st[lastIdx];
        sc += startT[st[0]] + endT[lastTag] + lg[(T_ - 1) * K_ + lastTag] * sm[T_ - 1];
        ll[b]   = sc - logZ;
        msum[b] = ms;
    }
}

// ---------------- Fallback (R1): per-batch sequential CRF ----------------------
__global__ __launch_bounds__(64) void crf_kernel(
    const float* __restrict__ outF,
    const int*   __restrict__ tags,
    const int*   __restrict__ mask,
    const float* __restrict__ trans,
    const float* __restrict__ startT,
    const float* __restrict__ endT,
    float* __restrict__ ws)
{
    __shared__ float se[T_ * K_];
    __shared__ float sm[T_];
    __shared__ int   st[T_];
    const int b = blockIdx.x;
    const int lane = threadIdx.x;

    const float* lg = outF + 1 + (size_t)b * T_ * K_;
    for (int i = lane; i < T_ * K_; i += 64) se[i] = lg[i];
    for (int t = lane; t < T_; t += 64) {
        sm[t] = (float)mask[b * T_ + t];
        st[t] = tags[b * T_ + t];
    }
    __syncthreads();

    const int jc = lane < K_ ? lane : K_ - 1;
    float ET[K_];
    #pragma unroll
    for (int i = 0; i < K_; ++i) ET[i] = __expf(trans[i * K_ + jc]);

    float a0   = startT[jc] + se[jc];
    float r0   = __shfl(a0, 0, 64);
    float aRel = a0 - r0;
    float C    = r0;

    for (int t = 1; t < T_; ++t) {
        if (sm[t] != 0.0f) {
            float e = __expf(aRel);
            float s = 0.0f;
            #pragma unroll
            for (int i = 0; i < K_; ++i)
                s = fmaf(__shfl(e, i, 64), ET[i], s);
            float raw = __logf(s) + se[t * K_ + jc];
            float rr  = __shfl(raw, 0, 64);
            aRel = raw - rr;
            C   += rr;
        }
    }

    float contrib = (lane < K_) ? __expf(aRel + endT[jc]) : 0.0f;
    #pragma unroll
    for (int off = 32; off >= 1; off >>= 1) contrib += __shfl_xor(contrib, off, 64);
    const float logZ = C + __logf(contrib);

    float sc = 0.0f, ms = 0.0f;
    for (int t = lane; t < T_; t += 64) {
        const float mt = sm[t];
        ms += mt;
        if (t < T_ - 1) {
            const int ct = st[t], nt2 = st[t + 1];
            sc += trans[ct * K_ + nt2] * sm[t + 1] + se[t * K_ + ct] * mt;
        }
    }
    #pragma unroll
    for (int off = 32; off >= 1; off >>= 1) {
        sc += __shfl_xor(sc, off, 64);
        ms += __shfl_xor(ms, off, 64);
    }
    if (lane == 0) {
        const int lastIdx = (int)ms - 1;
        const int lastTag = st[lastIdx];
        sc += startT[st[0]] + endT[lastTag] + se[(T_ - 1) * K_ + lastTag] * sm[T_ - 1];
        ws[b]      = sc - logZ;
        ws[B_ + b] = ms;
    }
}

// ---------------- Kernel 3: loss = -sum(ll) / sum(mask) ------------------------
__global__ __launch_bounds__(64) void fin_kernel(
    const float* __restrict__ ll, const float* __restrict__ msum,
    float* __restrict__ outF)
{
    const int lane = threadIdx.x;
    float l = ll[lane];
    float m = msum[lane];
    #pragma unroll
    for (int off = 32; off >= 1; off >>= 1) {
        l += __shfl_xor(l, off, 64);
        m += __shfl_xor(m, off, 64);
    }
    if (lane == 0) outF[0] = -l / m;
}

extern "C" void kernel_launch(void* const* d_in, const int* in_sizes, int n_in,
                              void* d_out, int out_size, void* d_ws, size_t ws_size,
                              hipStream_t stream) {
    const float* A     = (const float*)d_in[0];   // vectors [64,512,768] f32
    const int*   tags  = (const int*)  d_in[1];   // targets [64,512] i32
    const int*   mask  = (const int*)  d_in[2];   // mask    [64,512] i32
    const float* W     = (const float*)d_in[3];   // W [21,768] f32
    const float* bias  = (const float*)d_in[4];   // b [21]
    const float* trans = (const float*)d_in[5];   // transitions [21,21]
    const float* stT   = (const float*)d_in[6];   // start_trans [21]
    const float* enT   = (const float*)d_in[7];   // end_trans [21]
    float* outF = (float*)d_out;
    float* ws   = (float*)d_ws;

    proj_kernel<<<256, 512, 0, stream>>>(A, W, bias, outF);

    // ws layout (floats): G[64*32*448] | SC[64*32] | ll[64] | ms[64]
    const size_t gFloats  = (size_t)B_ * NCHUNK * GSTRIDE;
    const size_t scOff    = gFloats;
    const size_t llOff    = gFloats + (size_t)B_ * NCHUNK;
    const size_t msOff    = llOff + B_;
    const size_t needBytes = (msOff + B_) * sizeof(float);

    if (ws_size >= needBytes) {
        float* G   = ws;
        float* SC  = ws + scOff;
        float* llp = ws + llOff;
        float* msv = ws + msOff;
        chunk_kernel<<<dim3(NCHUNK, B_), 64, 0, stream>>>(outF, mask, trans, G, SC);
        scan_kernel<<<B_, 64, 0, stream>>>(outF, tags, mask, trans, stT, enT, G, SC, llp, msv);
        fin_kernel<<<1, 64, 0, stream>>>(llp, msv, outF);
    } else {
        crf_kernel<<<B_, 64, 0, stream>>>(outF, tags, mask, trans, stT, enT, ws);
        fin_kernel<<<1, 64, 0, stream>>>(ws, ws + B_, outF);
    }
}

// Round 5
// 225.908 us; speedup vs baseline: 1.0264x; 1.0264x over previous
//
#include <hip/hip_runtime.h>

#define B_ 64
#define T_ 512
#define D_ 768
#define K_ 21
#define NCHUNK 32    // chunks over t=1..511
#define CLEN 16      // steps per chunk
#define GSTRIDE 448  // padded 21*21
#define LOG21 3.0445224377234229965f

using f16x8 = __attribute__((ext_vector_type(8))) _Float16;
using f32x4 = __attribute__((ext_vector_type(4))) float;

// ---------------- Kernel 1: logits[32768,21] = A[32768,768] @ W^T + b ----------
// MFMA f16 (fp32 accumulate). One wave = 16 rows x {cols 0-15, cols 16-20}.
// 24 K-steps of 16x16x32. A,W converted f32->f16 inline; no LDS, no barriers.
// Layout (verified m89/m91): arg0 A[m=lane&15][k=(lane>>4)*8+j],
// arg1 B[k=(lane>>4)*8+j][n=lane&15], C/D col=lane&15, row=(lane>>4)*4+reg.
__global__ __launch_bounds__(256) void proj_kernel(
    const float* __restrict__ A,
    const float* __restrict__ W,
    const float* __restrict__ bias,
    float* __restrict__ out)            // d_out: [0]=loss, [1..]=logits
{
    const int lane = threadIdx.x & 63;
    const int wave = threadIdx.x >> 6;
    const int row0 = (blockIdx.x * 4 + wave) * 16;   // 512 blocks * 4 waves * 16 = 32768
    const int m = lane & 15;
    const int kb = (lane >> 4) * 8;                  // quad k-offset

    const float* __restrict__ Ar  = A + (size_t)(row0 + m) * D_ + kb;
    const float* __restrict__ Wr0 = W + (size_t)m * D_ + kb;
    const int n1 = (16 + m < K_) ? 16 + m : K_ - 1;  // clamp: cols 21..31 unstored
    const float* __restrict__ Wr1 = W + (size_t)n1 * D_ + kb;

    f32x4 acc0 = {0.f, 0.f, 0.f, 0.f};
    f32x4 acc1 = {0.f, 0.f, 0.f, 0.f};

    #pragma unroll 8
    for (int s = 0; s < 24; ++s) {
        const float4 aL = *(const float4*)(Ar  + s * 32);
        const float4 aH = *(const float4*)(Ar  + s * 32 + 4);
        const float4 bL = *(const float4*)(Wr0 + s * 32);
        const float4 bH = *(const float4*)(Wr0 + s * 32 + 4);
        const float4 cL = *(const float4*)(Wr1 + s * 32);
        const float4 cH = *(const float4*)(Wr1 + s * 32 + 4);
        f16x8 af, bf, cf;
        af[0]=(_Float16)aL.x; af[1]=(_Float16)aL.y; af[2]=(_Float16)aL.z; af[3]=(_Float16)aL.w;
        af[4]=(_Float16)aH.x; af[5]=(_Float16)aH.y; af[6]=(_Float16)aH.z; af[7]=(_Float16)aH.w;
        bf[0]=(_Float16)bL.x; bf[1]=(_Float16)bL.y; bf[2]=(_Float16)bL.z; bf[3]=(_Float16)bL.w;
        bf[4]=(_Float16)bH.x; bf[5]=(_Float16)bH.y; bf[6]=(_Float16)bH.z; bf[7]=(_Float16)bH.w;
        cf[0]=(_Float16)cL.x; cf[1]=(_Float16)cL.y; cf[2]=(_Float16)cL.z; cf[3]=(_Float16)cL.w;
        cf[4]=(_Float16)cH.x; cf[5]=(_Float16)cH.y; cf[6]=(_Float16)cH.z; cf[7]=(_Float16)cH.w;
        acc0 = __builtin_amdgcn_mfma_f32_16x16x32_f16(af, bf, acc0, 0, 0, 0);
        acc1 = __builtin_amdgcn_mfma_f32_16x16x32_f16(af, cf, acc1, 0, 0, 0);
    }

    // store: col=lane&15, row=(lane>>4)*4+reg
    const int rbase = row0 + (lane >> 4) * 4;
    {
        const float bb = bias[m];
        float* o = out + 1 + (size_t)rbase * K_ + m;
        #pragma unroll
        for (int r = 0; r < 4; ++r) o[(size_t)r * K_] = acc0[r] + bb;
    }
    const int col2 = 16 + m;
    if (col2 < K_) {
        const float bb = bias[col2];
        float* o = out + 1 + (size_t)rbase * K_ + col2;
        #pragma unroll
        for (int r = 0; r < 4; ++r) o[(size_t)r * K_] = acc1[r] + bb;
    }
}

// ---------------- Kernel 2a: per-(batch,chunk) transfer-matrix product --------
// G_c = Prod_{t in chunk, mask=1} (ET * diag(em_t)) / 21^n, em normalized by
// per-step max. One wave per task; lane l<63 -> (row i = l/3, colgroup jg = l%3).
__global__ __launch_bounds__(64) void chunk_kernel(
    const float* __restrict__ outF,
    const int*   __restrict__ mask,
    const float* __restrict__ trans,
    float* __restrict__ G,
    float* __restrict__ SC)
{
    __shared__ float M0[441], M1[441];
    __shared__ float sET[441];
    __shared__ float em[CLEN * K_];
    __shared__ float smx[CLEN];
    __shared__ int   smask[CLEN];

    const int c = blockIdx.x;
    const int b = blockIdx.y;
    const int lane = threadIdx.x;
    const int t0 = c * CLEN + 1;
    const int nst = min(CLEN, T_ - t0);     // 16, except 15 for last chunk
    const int i_ = lane / 3;
    const int jg = lane - i_ * 3;
    const bool act = lane < 63;

    const float* lg = outF + 1 + (size_t)b * T_ * K_;
    for (int idx = lane; idx < nst * K_; idx += 64) em[idx] = lg[t0 * K_ + idx];
    if (lane < nst) smask[lane] = mask[b * T_ + t0 + lane];
    for (int idx = lane; idx < 441; idx += 64) {
        M0[idx] = (idx % 22 == 0) ? 1.0f : 0.0f;     // identity
        sET[idx] = __expf(trans[idx]);               // coalesced trans read
    }
    __syncthreads();

    if (lane < nst) {
        float mx = -1e30f;
        for (int j = 0; j < K_; ++j) mx = fmaxf(mx, em[lane * K_ + j]);
        smx[lane] = mx;
    }
    __syncthreads();
    for (int idx = lane; idx < nst * K_; idx += 64)
        em[idx] = __expf(em[idx] - smx[idx / K_]) * (1.0f / 21.0f);

    float ETc[K_ * 7];
    if (act) {
        #pragma unroll
        for (int mm = 0; mm < K_; ++mm) {
            #pragma unroll
            for (int q = 0; q < 7; ++q)
                ETc[mm * 7 + q] = sET[mm * K_ + jg * 7 + q];
        }
    }
    __syncthreads();

    int cur = 0;
    for (int s = 0; s < nst; ++s) {
        if (smask[s] != 0) {                 // wave-uniform
            const float* Mr = cur ? M1 : M0;
            float*       Mw = cur ? M0 : M1;
            float facc[7] = {0.f,0.f,0.f,0.f,0.f,0.f,0.f};
            if (act) {
                #pragma unroll
                for (int mm = 0; mm < K_; ++mm) {
                    const float lm = Mr[i_ * K_ + mm];
                    #pragma unroll
                    for (int q = 0; q < 7; ++q)
                        facc[q] = fmaf(lm, ETc[mm * 7 + q], facc[q]);
                }
            }
            __syncthreads();
            if (act) {
                #pragma unroll
                for (int q = 0; q < 7; ++q)
                    Mw[i_ * K_ + jg * 7 + q] = facc[q] * em[s * K_ + jg * 7 + q];
            }
            __syncthreads();
            cur ^= 1;
        }
    }

    float* Gc = G + (size_t)(b * NCHUNK + c) * GSTRIDE;
    const float* Mf = cur ? M1 : M0;
    for (int idx = lane; idx < 441; idx += 64) Gc[idx] = Mf[idx];
    if (lane == 0) {
        float sc = 0.0f;
        for (int s = 0; s < nst; ++s)
            if (smask[s] != 0) sc += smx[s] + LOG21;
        SC[b * NCHUNK + c] = sc;
    }
}

// ---------------- Kernel 2b: 32-step scan + gold score per batch ---------------
// Whole per-batch G (56 KB) staged into LDS upfront with deep load pipeline.
__global__ __launch_bounds__(64) void scan_kernel(
    const float* __restrict__ outF,
    const int*   __restrict__ tags,
    const int*   __restrict__ mask,
    const float* __restrict__ trans,
    const float* __restrict__ startT,
    const float* __restrict__ endT,
    const float* __restrict__ G,
    const float* __restrict__ SC,
    float* __restrict__ ll,
    float* __restrict__ msum)
{
    __shared__ float sG[NCHUNK * GSTRIDE];   // 57344 B
    __shared__ float sv[24];
    __shared__ float sm[T_];
    __shared__ int   st[T_];
    const int b = blockIdx.x;
    const int lane = threadIdx.x;
    const int jc = min(lane, K_ - 1);
    const float* lg = outF + 1 + (size_t)b * T_ * K_;
    const float* Gb = G + (size_t)b * NCHUNK * GSTRIDE;

    {
        const float4* Gf4 = (const float4*)Gb;
        float4* dst = (float4*)sG;
        for (int j = lane; j < NCHUNK * GSTRIDE / 4; j += 64) dst[j] = Gf4[j];
    }
    for (int t = lane; t < T_; t += 64) {
        sm[t] = (float)mask[b * T_ + t];
        st[t] = tags[b * T_ + t];
    }
    const float scv = (lane < NCHUNK) ? SC[b * NCHUNK + lane] : 0.0f;

    float val = (lane < K_) ? startT[lane] + lg[lane] : -1e30f;
    float mx = val;
    #pragma unroll
    for (int off = 32; off >= 1; off >>= 1) mx = fmaxf(mx, __shfl_xor(mx, off, 64));
    float v = (lane < K_) ? __expf(val - mx) : 0.0f;
    float C = mx;
    __syncthreads();

    for (int c = 0; c < NCHUNK; ++c) {
        if (lane < K_) sv[lane] = v;
        __syncthreads();
        const float* Gc = sG + c * GSTRIDE;
        float a0 = 0.f, a1 = 0.f, a2 = 0.f;
        #pragma unroll
        for (int i = 0; i < K_; i += 3) {
            a0 = fmaf(sv[i],     Gc[i * K_ + jc],       a0);
            a1 = fmaf(sv[i + 1], Gc[(i + 1) * K_ + jc], a1);
            a2 = fmaf(sv[i + 2], Gc[(i + 2) * K_ + jc], a2);
        }
        const float s = a0 + a1 + a2;
        C += __shfl(scv, c, 64);
        float m2 = (lane < K_) ? s : 0.0f;
        #pragma unroll
        for (int off = 32; off >= 1; off >>= 1) m2 = fmaxf(m2, __shfl_xor(m2, off, 64));
        v = (lane < K_) ? s / m2 : 0.0f;
        C += __logf(m2);
        __syncthreads();
    }

    float term = (lane < K_) ? v * __expf(endT[lane]) : 0.0f;
    #pragma unroll
    for (int off = 32; off >= 1; off >>= 1) term += __shfl_xor(term, off, 64);
    const float logZ = C + __logf(term);

    float sc = 0.0f, ms = 0.0f;
    for (int t = lane; t < T_; t += 64) {
        const float mt = sm[t];
        ms += mt;
        if (t < T_ - 1) {
            const int ct = st[t], nt2 = st[t + 1];
            sc += trans[ct * K_ + nt2] * sm[t + 1] + lg[t * K_ + ct] * mt;
        }
    }
    #pragma unroll
    for (int off = 32; off >= 1; off >>= 1) {
        sc += __shfl_xor(sc, off, 64);
        ms += __shfl_xor(ms, off, 64);
    }
    if (lane == 0) {
        const int lastIdx = (int)ms - 1;
        const int lastTag = st[lastIdx];
        sc += startT[st[0]] + endT[lastTag] + lg[(T_ - 1) * K_ + lastTag] * sm[T_ - 1];
        ll[b]   = sc - logZ;
        msum[b] = ms;
    }
}

// ---------------- Fallback (R1): per-batch sequential CRF ----------------------
__global__ __launch_bounds__(64) void crf_kernel(
    const float* __restrict__ outF,
    const int*   __restrict__ tags,
    const int*   __restrict__ mask,
    const float* __restrict__ trans,
    const float* __restrict__ startT,
    const float* __restrict__ endT,
    float* __restrict__ ws)
{
    __shared__ float se[T_ * K_];
    __shared__ float sm[T_];
    __shared__ int   st[T_];
    const int b = blockIdx.x;
    const int lane = threadIdx.x;

    const float* lg = outF + 1 + (size_t)b * T_ * K_;
    for (int i = lane; i < T_ * K_; i += 64) se[i] = lg[i];
    for (int t = lane; t < T_; t += 64) {
        sm[t] = (float)mask[b * T_ + t];
        st[t] = tags[b * T_ + t];
    }
    __syncthreads();

    const int jc = lane < K_ ? lane : K_ - 1;
    float ET[K_];
    #pragma unroll
    for (int i = 0; i < K_; ++i) ET[i] = __expf(trans[i * K_ + jc]);

    float a0   = startT[jc] + se[jc];
    float r0   = __shfl(a0, 0, 64);
    float aRel = a0 - r0;
    float C    = r0;

    for (int t = 1; t < T_; ++t) {
        if (sm[t] != 0.0f) {
            float e = __expf(aRel);
            float s = 0.0f;
            #pragma unroll
            for (int i = 0; i < K_; ++i)
                s = fmaf(__shfl(e, i, 64), ET[i], s);
            float raw = __logf(s) + se[t * K_ + jc];
            float rr  = __shfl(raw, 0, 64);
            aRel = raw - rr;
            C   += rr;
        }
    }

    float contrib = (lane < K_) ? __expf(aRel + endT[jc]) : 0.0f;
    #pragma unroll
    for (int off = 32; off >= 1; off >>= 1) contrib += __shfl_xor(contrib, off, 64);
    const float logZ = C + __logf(contrib);

    float sc = 0.0f, ms = 0.0f;
    for (int t = lane; t < T_; t += 64) {
        const float mt = sm[t];
        ms += mt;
        if (t < T_ - 1) {
            const int ct = st[t], nt2 = st[t + 1];
            sc += trans[ct * K_ + nt2] * sm[t + 1] + se[t * K_ + ct] * mt;
        }
    }
    #pragma unroll
    for (int off = 32; off >= 1; off >>= 1) {
        sc += __shfl_xor(sc, off, 64);
        ms += __shfl_xor(ms, off, 64);
    }
    if (lane == 0) {
        const int lastIdx = (int)ms - 1;
        const int lastTag = st[lastIdx];
        sc += startT[st[0]] + endT[lastTag] + se[(T_ - 1) * K_ + lastTag] * sm[T_ - 1];
        ws[b]      = sc - logZ;
        ws[B_ + b] = ms;
    }
}

// ---------------- Kernel 3: loss = -sum(ll) / sum(mask) ------------------------
__global__ __launch_bounds__(64) void fin_kernel(
    const float* __restrict__ ll, const float* __restrict__ msum,
    float* __restrict__ outF)
{
    const int lane = threadIdx.x;
    float l = ll[lane];
    float m = msum[lane];
    #pragma unroll
    for (int off = 32; off >= 1; off >>= 1) {
        l += __shfl_xor(l, off, 64);
        m += __shfl_xor(m, off, 64);
    }
    if (lane == 0) outF[0] = -l / m;
}

extern "C" void kernel_launch(void* const* d_in, const int* in_sizes, int n_in,
                              void* d_out, int out_size, void* d_ws, size_t ws_size,
                              hipStream_t stream) {
    const float* A     = (const float*)d_in[0];   // vectors [64,512,768] f32
    const int*   tags  = (const int*)  d_in[1];   // targets [64,512] i32
    const int*   mask  = (const int*)  d_in[2];   // mask    [64,512] i32
    const float* W     = (const float*)d_in[3];   // W [21,768] f32
    const float* bias  = (const float*)d_in[4];   // b [21]
    const float* trans = (const float*)d_in[5];   // transitions [21,21]
    const float* stT   = (const float*)d_in[6];   // start_trans [21]
    const float* enT   = (const float*)d_in[7];   // end_trans [21]
    float* outF = (float*)d_out;
    float* ws   = (float*)d_ws;

    proj_kernel<<<512, 256, 0, stream>>>(A, W, bias, outF);

    // ws layout (floats): G[64*32*448] | SC[64*32] | ll[64] | ms[64]
    const size_t gFloats  = (size_t)B_ * NCHUNK * GSTRIDE;
    const size_t scOff    = gFloats;
    const size_t llOff    = gFloats + (size_t)B_ * NCHUNK;
    const size_t msOff    = llOff + B_;
    const size_t needBytes = (msOff + B_) * sizeof(float);

    if (ws_size >= needBytes) {
        float* G   = ws;
        float* SC  = ws + scOff;
        float* llp = ws + llOff;
        float* msv = ws + msOff;
        chunk_kernel<<<dim3(NCHUNK, B_), 64, 0, stream>>>(outF, mask, trans, G, SC);
        scan_kernel<<<B_, 64, 0, stream>>>(outF, tags, mask, trans, stT, enT, G, SC, llp, msv);
        fin_kernel<<<1, 64, 0, stream>>>(llp, msv, outF);
    } else {
        crf_kernel<<<B_, 64, 0, stream>>>(outF, tags, mask, trans, stT, enT, ws);
        fin_kernel<<<1, 64, 0, stream>>>(ws, ws + B_, outF);
    }
}

// Round 6
// 225.654 us; speedup vs baseline: 1.0276x; 1.0011x over previous
//
#include <hip/hip_runtime.h>

#define B_ 64
#define T_ 512
#define D_ 768
#define K_ 21
#define NCHUNK 32    // chunks per batch: (j,w) -> j*4+w, steps t=64j+16w..+15 (t=0 skipped)
#define GSTRIDE 448  // padded 21*21
#define LOG21 3.0445224377234229965f

using f16x8 = __attribute__((ext_vector_type(8))) _Float16;
using f32x4 = __attribute__((ext_vector_type(4))) float;

// ---- Kernel 1 (fused): logits = A@W^T+b (MFMA f16) + per-wave 16-step -------
// ---- transfer-matrix product G_c = Prod (ET*diag(em_t))/21^n ----------------
// Block = (b, j): 64 rows b*512+j*64.. ; wave w: rows +16w via 16x16x32 MFMA,
// then the product for chunk c=j*4+w using ONLY its own 16 emit rows (LDS).
// unroll 2 on the K-loop keeps VGPR modest (no spill).
__global__ __launch_bounds__(256) void proj_chunk_kernel(
    const float* __restrict__ A,
    const float* __restrict__ W,
    const float* __restrict__ bias,
    const int*   __restrict__ mask,
    const float* __restrict__ trans,
    float* __restrict__ out,            // d_out: [0]=loss, [1..]=logits
    float* __restrict__ G,
    float* __restrict__ SC)
{
    __shared__ float sET[441];          // exp(trans)
    __shared__ float em[4][16 * K_];    // per-wave raw logits -> normalized probs
    __shared__ float smx[4][16];
    __shared__ int   smk[4][16];
    __shared__ float M[4][2][441];      // per-wave product double-buffer

    const int tid  = threadIdx.x;
    const int lane = tid & 63;
    const int w    = tid >> 6;
    const int blk  = blockIdx.x;        // = b*8 + j
    const int b    = blk >> 3;
    const int j    = blk & 7;
    const int row0 = blk * 64 + w * 16;
    const int m    = lane & 15;
    const int quad = lane >> 4;
    const int kb   = quad * 8;

    for (int idx = tid; idx < 441; idx += 256) sET[idx] = __expf(trans[idx]);

    // ---- MFMA phase (layout verified m89/m91; R5-correct) ----
    const float* __restrict__ Ar  = A + (size_t)(row0 + m) * D_ + kb;
    const float* __restrict__ Wr0 = W + (size_t)m * D_ + kb;
    const int n1 = (16 + m < K_) ? 16 + m : K_ - 1;
    const float* __restrict__ Wr1 = W + (size_t)n1 * D_ + kb;

    f32x4 acc0 = {0.f, 0.f, 0.f, 0.f};
    f32x4 acc1 = {0.f, 0.f, 0.f, 0.f};

    #pragma unroll 2
    for (int s = 0; s < 24; ++s) {
        const float4 aL = *(const float4*)(Ar  + s * 32);
        const float4 aH = *(const float4*)(Ar  + s * 32 + 4);
        const float4 bL = *(const float4*)(Wr0 + s * 32);
        const float4 bH = *(const float4*)(Wr0 + s * 32 + 4);
        const float4 cL = *(const float4*)(Wr1 + s * 32);
        const float4 cH = *(const float4*)(Wr1 + s * 32 + 4);
        f16x8 af, bf, cf;
        af[0]=(_Float16)aL.x; af[1]=(_Float16)aL.y; af[2]=(_Float16)aL.z; af[3]=(_Float16)aL.w;
        af[4]=(_Float16)aH.x; af[5]=(_Float16)aH.y; af[6]=(_Float16)aH.z; af[7]=(_Float16)aH.w;
        bf[0]=(_Float16)bL.x; bf[1]=(_Float16)bL.y; bf[2]=(_Float16)bL.z; bf[3]=(_Float16)bL.w;
        bf[4]=(_Float16)bH.x; bf[5]=(_Float16)bH.y; bf[6]=(_Float16)bH.z; bf[7]=(_Float16)bH.w;
        cf[0]=(_Float16)cL.x; cf[1]=(_Float16)cL.y; cf[2]=(_Float16)cL.z; cf[3]=(_Float16)cL.w;
        cf[4]=(_Float16)cH.x; cf[5]=(_Float16)cH.y; cf[6]=(_Float16)cH.z; cf[7]=(_Float16)cH.w;
        acc0 = __builtin_amdgcn_mfma_f32_16x16x32_f16(af, bf, acc0, 0, 0, 0);
        acc1 = __builtin_amdgcn_mfma_f32_16x16x32_f16(af, cf, acc1, 0, 0, 0);
    }

    // epilogue: logits -> global AND own-wave LDS (C layout: col=lane&15, row=quad*4+reg)
    const int rloc = quad * 4;
    {
        const float bb = bias[m];
        float* o = out + 1 + (size_t)(row0 + rloc) * K_ + m;
        #pragma unroll
        for (int r = 0; r < 4; ++r) {
            const float v = acc0[r] + bb;
            o[(size_t)r * K_] = v;
            em[w][(rloc + r) * K_ + m] = v;
        }
    }
    const int col2 = 16 + m;
    if (col2 < K_) {
        const float bb = bias[col2];
        float* o = out + 1 + (size_t)(row0 + rloc) * K_ + col2;
        #pragma unroll
        for (int r = 0; r < 4; ++r) {
            const float v = acc1[r] + bb;
            o[(size_t)r * K_] = v;
            em[w][(rloc + r) * K_ + col2] = v;
        }
    }
    if (lane < 16) smk[w][lane] = mask[b * T_ + j * 64 + w * 16 + lane];
    __syncthreads();                    // A: em, smk, sET visible

    if (lane < 16) {
        float mx = -1e30f;
        #pragma unroll
        for (int c = 0; c < K_; ++c) mx = fmaxf(mx, em[w][lane * K_ + c]);
        smx[w][lane] = mx;
    }
    __syncthreads();                    // B: smx visible

    for (int idx = lane; idx < 16 * K_; idx += 64)
        em[w][idx] = __expf(em[w][idx] - smx[w][idx / K_]) * (1.0f / 21.0f);
    for (int idx = lane; idx < 441; idx += 64)
        M[w][0][idx] = (idx % 22 == 0) ? 1.0f : 0.0f;

    const int i_ = lane / 3;
    const int jg = lane - i_ * 3;
    const bool act = lane < 63;
    float ETc[K_ * 7];
    if (act) {
        #pragma unroll
        for (int mm = 0; mm < K_; ++mm) {
            #pragma unroll
            for (int q = 0; q < 7; ++q)
                ETc[mm * 7 + q] = sET[mm * K_ + jg * 7 + q];
        }
    }
    __syncthreads();                    // C: em normalized, M0 init

    // ---- per-wave 16-step product; volatile M reads give intra-wave ordering
    volatile float* Mv0 = M[w][0];
    volatile float* Mv1 = M[w][1];
    int cur = 0;
    const int startS = (j == 0 && w == 0) ? 1 : 0;   // skip t=0
    for (int sI = startS; sI < 16; ++sI) {
        if (smk[w][sI] != 0) {          // wave-uniform (broadcast LDS read)
            volatile float* Mr = cur ? Mv1 : Mv0;
            float*          Mw = cur ? M[w][0] : M[w][1];
            if (act) {
                float facc[7] = {0.f,0.f,0.f,0.f,0.f,0.f,0.f};
                #pragma unroll
                for (int mm = 0; mm < K_; ++mm) {
                    const float lm = Mr[i_ * K_ + mm];
                    #pragma unroll
                    for (int q = 0; q < 7; ++q)
                        facc[q] = fmaf(lm, ETc[mm * 7 + q], facc[q]);
                }
                #pragma unroll
                for (int q = 0; q < 7; ++q)
                    Mw[i_ * K_ + jg * 7 + q] = facc[q] * em[w][sI * K_ + jg * 7 + q];
            }
            cur ^= 1;
        }
    }

    volatile float* Mf = cur ? Mv1 : Mv0;
    float* Gc = G + (size_t)(b * NCHUNK + j * 4 + w) * GSTRIDE;
    for (int idx = lane; idx < 441; idx += 64) Gc[idx] = Mf[idx];
    if (lane == 0) {
        float sc = 0.0f;
        for (int sI = startS; sI < 16; ++sI)
            if (smk[w][sI] != 0) sc += smx[w][sI] + LOG21;
        SC[b * NCHUNK + j * 4 + w] = sc;
    }
}

// ---------------- Kernel 2: 32-step scan + gold score per batch ---------------
__global__ __launch_bounds__(64) void scan_kernel(
    const float* __restrict__ outF,
    const int*   __restrict__ tags,
    const int*   __restrict__ mask,
    const float* __restrict__ trans,
    const float* __restrict__ startT,
    const float* __restrict__ endT,
    const float* __restrict__ G,
    const float* __restrict__ SC,
    float* __restrict__ ll,
    float* __restrict__ msum)
{
    __shared__ float sG[NCHUNK * GSTRIDE];   // 57344 B
    __shared__ float sv[24];
    __shared__ float sm[T_];
    __shared__ int   st[T_];
    const int b = blockIdx.x;
    const int lane = threadIdx.x;
    const int jc = min(lane, K_ - 1);
    const float* lg = outF + 1 + (size_t)b * T_ * K_;
    const float* Gb = G + (size_t)b * NCHUNK * GSTRIDE;

    {
        const float4* Gf4 = (const float4*)Gb;
        float4* dst = (float4*)sG;
        for (int i = lane; i < NCHUNK * GSTRIDE / 4; i += 64) dst[i] = Gf4[i];
    }
    for (int t = lane; t < T_; t += 64) {
        sm[t] = (float)mask[b * T_ + t];
        st[t] = tags[b * T_ + t];
    }
    const float scv = (lane < NCHUNK) ? SC[b * NCHUNK + lane] : 0.0f;

    float val = (lane < K_) ? startT[lane] + lg[lane] : -1e30f;
    float mx = val;
    #pragma unroll
    for (int off = 32; off >= 1; off >>= 1) mx = fmaxf(mx, __shfl_xor(mx, off, 64));
    float v = (lane < K_) ? __expf(val - mx) : 0.0f;
    float C = mx;
    __syncthreads();

    for (int c = 0; c < NCHUNK; ++c) {
        if (lane < K_) sv[lane] = v;
        __syncthreads();
        const float* Gc = sG + c * GSTRIDE;
        float a0 = 0.f, a1 = 0.f, a2 = 0.f;
        #pragma unroll
        for (int i = 0; i < K_; i += 3) {
            a0 = fmaf(sv[i],     Gc[i * K_ + jc],       a0);
            a1 = fmaf(sv[i + 1], Gc[(i + 1) * K_ + jc], a1);
            a2 = fmaf(sv[i + 2], Gc[(i + 2) * K_ + jc], a2);
        }
        const float s = a0 + a1 + a2;
        C += __shfl(scv, c, 64);
        float m2 = (lane < K_) ? s : 0.0f;
        #pragma unroll
        for (int off = 32; off >= 1; off >>= 1) m2 = fmaxf(m2, __shfl_xor(m2, off, 64));
        v = (lane < K_) ? s / m2 : 0.0f;
        C += __logf(m2);
        __syncthreads();
    }

    float term = (lane < K_) ? v * __expf(endT[lane]) : 0.0f;
    #pragma unroll
    for (int off = 32; off >= 1; off >>= 1) term += __shfl_xor(term, off, 64);
    const float logZ = C + __logf(term);

    float sc = 0.0f, ms = 0.0f;
    for (int t = lane; t < T_; t += 64) {
        const float mt = sm[t];
        ms += mt;
        if (t < T_ - 1) {
            const int ct = st[t], nt2 = st[t + 1];
            sc += trans[ct * K_ + nt2] * sm[t + 1] + lg[t * K_ + ct] * mt;
        }
    }
    #pragma unroll
    for (int off = 32; off >= 1; off >>= 1) {
        sc += __shfl_xor(sc, off, 64);
        ms += __shfl_xor(ms, off, 64);
    }
    if (lane == 0) {
        const int lastIdx = (int)ms - 1;
        const int lastTag = st[lastIdx];
        sc += startT[st[0]] + endT[lastTag] + lg[(T_ - 1) * K_ + lastTag] * sm[T_ - 1];
        ll[b]   = sc - logZ;
        msum[b] = ms;
    }
}

// ---------------- Kernel 3: loss = -sum(ll) / sum(mask) ------------------------
__global__ __launch_bounds__(64) void fin_kernel(
    const float* __restrict__ ll, const float* __restrict__ msum,
    float* __restrict__ outF)
{
    const int lane = threadIdx.x;
    float l = ll[lane];
    float m = msum[lane];
    #pragma unroll
    for (int off = 32; off >= 1; off >>= 1) {
        l += __shfl_xor(l, off, 64);
        m += __shfl_xor(m, off, 64);
    }
    if (lane == 0) outF[0] = -l / m;
}

// ---------------- Fallback path (ws too small): proj + sequential CRF ----------
__global__ __launch_bounds__(256) void proj_kernel(
    const float* __restrict__ A,
    const float* __restrict__ W,
    const float* __restrict__ bias,
    float* __restrict__ out)
{
    const int lane = threadIdx.x & 63;
    const int wave = threadIdx.x >> 6;
    const int row0 = (blockIdx.x * 4 + wave) * 16;
    const int m = lane & 15;
    const int kb = (lane >> 4) * 8;

    const float* __restrict__ Ar  = A + (size_t)(row0 + m) * D_ + kb;
    const float* __restrict__ Wr0 = W + (size_t)m * D_ + kb;
    const int n1 = (16 + m < K_) ? 16 + m : K_ - 1;
    const float* __restrict__ Wr1 = W + (size_t)n1 * D_ + kb;

    f32x4 acc0 = {0.f, 0.f, 0.f, 0.f};
    f32x4 acc1 = {0.f, 0.f, 0.f, 0.f};

    #pragma unroll 2
    for (int s = 0; s < 24; ++s) {
        const float4 aL = *(const float4*)(Ar  + s * 32);
        const float4 aH = *(const float4*)(Ar  + s * 32 + 4);
        const float4 bL = *(const float4*)(Wr0 + s * 32);
        const float4 bH = *(const float4*)(Wr0 + s * 32 + 4);
        const float4 cL = *(const float4*)(Wr1 + s * 32);
        const float4 cH = *(const float4*)(Wr1 + s * 32 + 4);
        f16x8 af, bf, cf;
        af[0]=(_Float16)aL.x; af[1]=(_Float16)aL.y; af[2]=(_Float16)aL.z; af[3]=(_Float16)aL.w;
        af[4]=(_Float16)aH.x; af[5]=(_Float16)aH.y; af[6]=(_Float16)aH.z; af[7]=(_Float16)aH.w;
        bf[0]=(_Float16)bL.x; bf[1]=(_Float16)bL.y; bf[2]=(_Float16)bL.z; bf[3]=(_Float16)bL.w;
        bf[4]=(_Float16)bH.x; bf[5]=(_Float16)bH.y; bf[6]=(_Float16)bH.z; bf[7]=(_Float16)bH.w;
        cf[0]=(_Float16)cL.x; cf[1]=(_Float16)cL.y; cf[2]=(_Float16)cL.z; cf[3]=(_Float16)cL.w;
        cf[4]=(_Float16)cH.x; cf[5]=(_Float16)cH.y; cf[6]=(_Float16)cH.z; cf[7]=(_Float16)cH.w;
        acc0 = __builtin_amdgcn_mfma_f32_16x16x32_f16(af, bf, acc0, 0, 0, 0);
        acc1 = __builtin_amdgcn_mfma_f32_16x16x32_f16(af, cf, acc1, 0, 0, 0);
    }

    const int rbase = row0 + (lane >> 4) * 4;
    {
        const float bb = bias[m];
        float* o = out + 1 + (size_t)rbase * K_ + m;
        #pragma unroll
        for (int r = 0; r < 4; ++r) o[(size_t)r * K_] = acc0[r] + bb;
    }
    const int col2 = 16 + m;
    if (col2 < K_) {
        const float bb = bias[col2];
        float* o = out + 1 + (size_t)rbase * K_ + col2;
        #pragma unroll
        for (int r = 0; r < 4; ++r) o[(size_t)r * K_] = acc1[r] + bb;
    }
}

__global__ __launch_bounds__(64) void crf_kernel(
    const float* __restrict__ outF,
    const int*   __restrict__ tags,
    const int*   __restrict__ mask,
    const float* __restrict__ trans,
    const float* __restrict__ startT,
    const float* __restrict__ endT,
    float* __restrict__ ws)
{
    __shared__ float se[T_ * K_];
    __shared__ float sm[T_];
    __shared__ int   st[T_];
    const int b = blockIdx.x;
    const int lane = threadIdx.x;

    const float* lg = outF + 1 + (size_t)b * T_ * K_;
    for (int i = lane; i < T_ * K_; i += 64) se[i] = lg[i];
    for (int t = lane; t < T_; t += 64) {
        sm[t] = (float)mask[b * T_ + t];
        st[t] = tags[b * T_ + t];
    }
    __syncthreads();

    const int jc = lane < K_ ? lane : K_ - 1;
    float ET[K_];
    #pragma unroll
    for (int i = 0; i < K_; ++i) ET[i] = __expf(trans[i * K_ + jc]);

    float a0   = startT[jc] + se[jc];
    float r0   = __shfl(a0, 0, 64);
    float aRel = a0 - r0;
    float C    = r0;

    for (int t = 1; t < T_; ++t) {
        if (sm[t] != 0.0f) {
            float e = __expf(aRel);
            float s = 0.0f;
            #pragma unroll
            for (int i = 0; i < K_; ++i)
                s = fmaf(__shfl(e, i, 64), ET[i], s);
            float raw = __logf(s) + se[t * K_ + jc];
            float rr  = __shfl(raw, 0, 64);
            aRel = raw - rr;
            C   += rr;
        }
    }

    float contrib = (lane < K_) ? __expf(aRel + endT[jc]) : 0.0f;
    #pragma unroll
    for (int off = 32; off >= 1; off >>= 1) contrib += __shfl_xor(contrib, off, 64);
    const float logZ = C + __logf(contrib);

    float sc = 0.0f, ms = 0.0f;
    for (int t = lane; t < T_; t += 64) {
        const float mt = sm[t];
        ms += mt;
        if (t < T_ - 1) {
            const int ct = st[t], nt2 = st[t + 1];
            sc += trans[ct * K_ + nt2] * sm[t + 1] + se[t * K_ + ct] * mt;
        }
    }
    #pragma unroll
    for (int off = 32; off >= 1; off >>= 1) {
        sc += __shfl_xor(sc, off, 64);
        ms += __shfl_xor(ms, off, 64);
    }
    if (lane == 0) {
        const int lastIdx = (int)ms - 1;
        const int lastTag = st[lastIdx];
        sc += startT[st[0]] + endT[lastTag] + se[(T_ - 1) * K_ + lastTag] * sm[T_ - 1];
        ws[b]      = sc - logZ;
        ws[B_ + b] = ms;
    }
}

extern "C" void kernel_launch(void* const* d_in, const int* in_sizes, int n_in,
                              void* d_out, int out_size, void* d_ws, size_t ws_size,
                              hipStream_t stream) {
    const float* A     = (const float*)d_in[0];   // vectors [64,512,768] f32
    const int*   tags  = (const int*)  d_in[1];   // targets [64,512] i32
    const int*   mask  = (const int*)  d_in[2];   // mask    [64,512] i32
    const float* W     = (const float*)d_in[3];   // W [21,768] f32
    const float* bias  = (const float*)d_in[4];   // b [21]
    const float* trans = (const float*)d_in[5];   // transitions [21,21]
    const float* stT   = (const float*)d_in[6];   // start_trans [21]
    const float* enT   = (const float*)d_in[7];   // end_trans [21]
    float* outF = (float*)d_out;
    float* ws   = (float*)d_ws;

    // ws layout (floats): G[64*32*448] | SC[64*32] | ll[64] | ms[64]
    const size_t gFloats  = (size_t)B_ * NCHUNK * GSTRIDE;
    const size_t scOff    = gFloats;
    const size_t llOff    = gFloats + (size_t)B_ * NCHUNK;
    const size_t msOff    = llOff + B_;
    const size_t needBytes = (msOff + B_) * sizeof(float);

    if (ws_size >= needBytes) {
        float* G   = ws;
        float* SC  = ws + scOff;
        float* llp = ws + llOff;
        float* msv = ws + msOff;
        proj_chunk_kernel<<<512, 256, 0, stream>>>(A, W, bias, mask, trans, outF, G, SC);
        scan_kernel<<<B_, 64, 0, stream>>>(outF, tags, mask, trans, stT, enT, G, SC, llp, msv);
        fin_kernel<<<1, 64, 0, stream>>>(llp, msv, outF);
    } else {
        proj_kernel<<<512, 256, 0, stream>>>(A, W, bias, outF);
        crf_kernel<<<B_, 64, 0, stream>>>(outF, tags, mask, trans, stT, enT, ws);
        fin_kernel<<<1, 64, 0, stream>>>(ws, ws + B_, outF);
    }
}

// Round 7
// 206.419 us; speedup vs baseline: 1.1233x; 1.0932x over previous
//
#include <hip/hip_runtime.h>

#define B_ 64
#define T_ 512
#define D_ 768
#define K_ 21
#define NCHUNK 32    // chunks over t=1..511
#define CLEN 16
#define GSTRIDE 448  // padded 21*21
#define LOG21 3.0445224377234229965f
#define WSTRIDE 776  // W LDS row stride (halves), mult of 8
#define ASTRIDE 136  // A LDS row stride (halves), mult of 8

using f16x8 = __attribute__((ext_vector_type(8))) _Float16;
using h16x4 = __attribute__((ext_vector_type(4))) _Float16;
using f32x4 = __attribute__((ext_vector_type(4))) float;

// ---------------- Kernel 1: logits = A@W^T + b, LDS-staged MFMA GEMM ----------
// Block = 64 rows, 256 thr (4 waves x 16 rows). W (f16) + double-buffered A
// tile (64x128 f16) in LDS; global loads fully coalesced; fragments are single
// ds_read_b128. Register-prefetch double buffer, 1 barrier/tile.
__global__ __launch_bounds__(256) void proj_kernel(
    const float* __restrict__ A,
    const float* __restrict__ W,
    const float* __restrict__ bias,
    float* __restrict__ out)            // d_out: [0]=loss, [1..]=logits
{
    __shared__ _Float16 Wh[K_ * WSTRIDE];     // 32592 B
    __shared__ _Float16 Ah[2][64 * ASTRIDE];  // 34816 B
    const int tid  = threadIdx.x;
    const int lane = tid & 63;
    const int w    = tid >> 6;
    const int m    = lane & 15;
    const int quad = lane >> 4;
    const size_t row0 = (size_t)blockIdx.x * 64;

    // stage W f32->f16 (coalesced)
    {
        const float4* Wg = (const float4*)W;
        for (int i = tid; i < K_ * D_ / 4; i += 256) {
            const float4 v = Wg[i];
            const int fi = i * 4;
            const int r = fi / D_;
            const int c = fi - r * D_;
            h16x4 h;
            h[0] = (_Float16)v.x; h[1] = (_Float16)v.y;
            h[2] = (_Float16)v.z; h[3] = (_Float16)v.w;
            *(h16x4*)(&Wh[r * WSTRIDE + c]) = h;
        }
    }

    // stage A tile 0 (coalesced: 8 float4/thread)
    float4 pf[8];
    #pragma unroll
    for (int j = 0; j < 8; ++j) {
        const int i = tid + j * 256;
        const int r = i >> 5, c4 = i & 31;
        pf[j] = *(const float4*)(A + (row0 + r) * D_ + c4 * 4);
    }
    #pragma unroll
    for (int j = 0; j < 8; ++j) {
        const int i = tid + j * 256;
        const int r = i >> 5, c4 = i & 31;
        h16x4 h;
        h[0] = (_Float16)pf[j].x; h[1] = (_Float16)pf[j].y;
        h[2] = (_Float16)pf[j].z; h[3] = (_Float16)pf[j].w;
        *(h16x4*)(&Ah[0][r * ASTRIDE + c4 * 4]) = h;
    }
    __syncthreads();

    f32x4 acc0 = {0.f, 0.f, 0.f, 0.f};
    f32x4 acc1 = {0.f, 0.f, 0.f, 0.f};
    const int n1 = (16 + m < K_) ? 16 + m : K_ - 1;

    for (int kt = 0; kt < 6; ++kt) {
        if (kt < 5) {
            #pragma unroll
            for (int j = 0; j < 8; ++j) {
                const int i = tid + j * 256;
                const int r = i >> 5, c4 = i & 31;
                pf[j] = *(const float4*)(A + (row0 + r) * D_ + (kt + 1) * 128 + c4 * 4);
            }
        }
        const _Float16* Ab = Ah[kt & 1];
        #pragma unroll
        for (int s = 0; s < 4; ++s) {
            const f16x8 af = *(const f16x8*)(&Ab[(w * 16 + m) * ASTRIDE + s * 32 + quad * 8]);
            const f16x8 bf = *(const f16x8*)(&Wh[m * WSTRIDE + kt * 128 + s * 32 + quad * 8]);
            const f16x8 cf = *(const f16x8*)(&Wh[n1 * WSTRIDE + kt * 128 + s * 32 + quad * 8]);
            acc0 = __builtin_amdgcn_mfma_f32_16x16x32_f16(af, bf, acc0, 0, 0, 0);
            acc1 = __builtin_amdgcn_mfma_f32_16x16x32_f16(af, cf, acc1, 0, 0, 0);
        }
        if (kt < 5) {
            _Float16* Aw = Ah[(kt + 1) & 1];
            #pragma unroll
            for (int j = 0; j < 8; ++j) {
                const int i = tid + j * 256;
                const int r = i >> 5, c4 = i & 31;
                h16x4 h;
                h[0] = (_Float16)pf[j].x; h[1] = (_Float16)pf[j].y;
                h[2] = (_Float16)pf[j].z; h[3] = (_Float16)pf[j].w;
                *(h16x4*)(&Aw[r * ASTRIDE + c4 * 4]) = h;
            }
        }
        __syncthreads();
    }

    // epilogue (C layout verified: col=lane&15, row=quad*4+reg)
    const size_t rbase = row0 + w * 16 + quad * 4;
    {
        const float bb = bias[m];
        float* o = out + 1 + rbase * K_ + m;
        #pragma unroll
        for (int r = 0; r < 4; ++r) o[(size_t)r * K_] = acc0[r] + bb;
    }
    const int col2 = 16 + m;
    if (col2 < K_) {
        const float bb = bias[col2];
        float* o = out + 1 + rbase * K_ + col2;
        #pragma unroll
        for (int r = 0; r < 4; ++r) o[(size_t)r * K_] = acc1[r] + bb;
    }
}

// ---------------- Kernel 2a: per-(batch,chunk) transfer-matrix product --------
// G_c = Prod_{t in chunk, mask=1} (ET*diag(em_t))/21^n. One wave per task;
// lane l<63 -> (row i=l/3, colgroup jg=l%3) owns 7 outputs. launch_bounds(64,1)
// gives the full VGPR budget so ETc[147] stays in registers (no scratch).
__global__ __launch_bounds__(64, 1) void chunk_kernel(
    const float* __restrict__ outF,
    const int*   __restrict__ mask,
    const float* __restrict__ trans,
    float* __restrict__ G,
    float* __restrict__ SC)
{
    __shared__ float M0[441], M1[441];
    __shared__ float sET[441];
    __shared__ float em[CLEN * K_];
    __shared__ float smx[CLEN];
    __shared__ int   smask[CLEN];

    const int c = blockIdx.x;
    const int b = blockIdx.y;
    const int lane = threadIdx.x;
    const int t0 = c * CLEN + 1;
    const int nst = min(CLEN, T_ - t0);     // 16, except 15 for last chunk
    const int i_ = lane / 3;
    const int jg = lane - i_ * 3;
    const bool act = lane < 63;

    const float* lg = outF + 1 + (size_t)b * T_ * K_;
    for (int idx = lane; idx < nst * K_; idx += 64) em[idx] = lg[t0 * K_ + idx];
    if (lane < nst) smask[lane] = mask[b * T_ + t0 + lane];
    for (int idx = lane; idx < 441; idx += 64) {
        M0[idx] = (idx % 22 == 0) ? 1.0f : 0.0f;
        sET[idx] = __expf(trans[idx]);
    }
    __syncthreads();

    if (lane < nst) {
        float mx = -1e30f;
        for (int j = 0; j < K_; ++j) mx = fmaxf(mx, em[lane * K_ + j]);
        smx[lane] = mx;
    }
    __syncthreads();
    for (int idx = lane; idx < nst * K_; idx += 64)
        em[idx] = __expf(em[idx] - smx[idx / K_]) * (1.0f / 21.0f);

    float ETc[K_ * 7];
    if (act) {
        #pragma unroll
        for (int mm = 0; mm < K_; ++mm) {
            #pragma unroll
            for (int q = 0; q < 7; ++q)
                ETc[mm * 7 + q] = sET[mm * K_ + jg * 7 + q];
        }
    }
    __syncthreads();

    int cur = 0;
    for (int s = 0; s < nst; ++s) {
        if (smask[s] != 0) {                 // wave-uniform
            const float* Mr = cur ? M1 : M0;
            float*       Mw = cur ? M0 : M1;
            float facc[7] = {0.f,0.f,0.f,0.f,0.f,0.f,0.f};
            if (act) {
                #pragma unroll
                for (int mm = 0; mm < K_; ++mm) {
                    const float lm = Mr[i_ * K_ + mm];
                    #pragma unroll
                    for (int q = 0; q < 7; ++q)
                        facc[q] = fmaf(lm, ETc[mm * 7 + q], facc[q]);
                }
            }
            __syncthreads();
            if (act) {
                #pragma unroll
                for (int q = 0; q < 7; ++q)
                    Mw[i_ * K_ + jg * 7 + q] = facc[q] * em[s * K_ + jg * 7 + q];
            }
            __syncthreads();
            cur ^= 1;
        }
    }

    float* Gc = G + (size_t)(b * NCHUNK + c) * GSTRIDE;
    const float* Mf = cur ? M1 : M0;
    for (int idx = lane; idx < 441; idx += 64) Gc[idx] = Mf[idx];
    if (lane == 0) {
        float sc = 0.0f;
        for (int s = 0; s < nst; ++s)
            if (smask[s] != 0) sc += smx[s] + LOG21;
        SC[b * NCHUNK + c] = sc;
    }
}

// ---------------- Kernel 2b: scan + gold score, 256 thr ------------------------
// 4 waves stage G (56KB) + masks; wave 0 runs the 32-step scan with shuffle-
// broadcast v and lane0-renorm (no per-iter barriers); waves 1-3 compute the
// gold-path score in parallel.
__global__ __launch_bounds__(256) void scan_kernel(
    const float* __restrict__ outF,
    const int*   __restrict__ tags,
    const int*   __restrict__ mask,
    const float* __restrict__ trans,
    const float* __restrict__ startT,
    const float* __restrict__ endT,
    const float* __restrict__ G,
    const float* __restrict__ SC,
    float* __restrict__ ll,
    float* __restrict__ msum)
{
    __shared__ float sG[NCHUNK * GSTRIDE];   // 57344 B
    __shared__ float sm[T_];
    __shared__ int   st[T_];
    __shared__ float part[8];
    const int tid = threadIdx.x;
    const int lane = tid & 63;
    const int w = tid >> 6;
    const int b = blockIdx.x;
    const float* lg = outF + 1 + (size_t)b * T_ * K_;

    {
        const float4* Gf4 = (const float4*)(G + (size_t)b * NCHUNK * GSTRIDE);
        float4* dst = (float4*)sG;
        for (int i = tid; i < NCHUNK * GSTRIDE / 4; i += 256) dst[i] = Gf4[i];
    }
    for (int t = tid; t < T_; t += 256) {
        sm[t] = (float)mask[b * T_ + t];
        st[t] = tags[b * T_ + t];
    }
    __syncthreads();

    float logZ = 0.0f;
    if (w == 0) {
        const float scv = (lane < NCHUNK) ? SC[b * NCHUNK + lane] : 0.0f;
        const int jc = min(lane, K_ - 1);
        float v = (lane < K_) ? __expf(startT[lane] + lg[lane]) : 0.0f;
        float C = 0.0f;
        for (int c = 0; c < NCHUNK; ++c) {
            const float* Gc = sG + c * GSTRIDE;
            float a0 = 0.f, a1 = 0.f, a2 = 0.f;
            #pragma unroll
            for (int i = 0; i < K_; i += 3) {
                a0 = fmaf(__shfl(v, i,     64), Gc[i * K_ + jc],       a0);
                a1 = fmaf(__shfl(v, i + 1, 64), Gc[(i + 1) * K_ + jc], a1);
                a2 = fmaf(__shfl(v, i + 2, 64), Gc[(i + 2) * K_ + jc], a2);
            }
            const float s = a0 + a1 + a2;
            const float s0 = __shfl(s, 0, 64);     // >0 always (all-positive G)
            v = s / s0;
            C += __logf(s0) + __shfl(scv, c, 64);
        }
        float term = (lane < K_) ? v * __expf(endT[lane]) : 0.0f;
        #pragma unroll
        for (int off = 16; off >= 1; off >>= 1) term += __shfl_xor(term, off, 64);
        term += __shfl_xor(term, 32, 64);
        logZ = C + __logf(term);
    } else {
        float sc = 0.0f, ms = 0.0f;
        for (int t = tid - 64; t < T_; t += 192) {
            const float mt = sm[t];
            ms += mt;
            if (t < T_ - 1) {
                const int ct = st[t], nt2 = st[t + 1];
                sc += trans[ct * K_ + nt2] * sm[t + 1] + lg[t * K_ + ct] * mt;
            }
        }
        #pragma unroll
        for (int off = 32; off >= 1; off >>= 1) {
            sc += __shfl_xor(sc, off, 64);
            ms += __shfl_xor(ms, off, 64);
        }
        if (lane == 0) { part[w] = sc; part[4 + w] = ms; }
    }
    __syncthreads();

    if (tid == 0) {
        float sc = part[1] + part[2] + part[3];
        float ms = part[5] + part[6] + part[7];
        const int lastIdx = (int)ms - 1;
        const int lastTag = st[lastIdx];
        sc += startT[st[0]] + endT[lastTag] + lg[(T_ - 1) * K_ + lastTag] * sm[T_ - 1];
        ll[b]   = sc - logZ;
        msum[b] = ms;
    }
}

// ---------------- Kernel 3: loss = -sum(ll) / sum(mask) ------------------------
__global__ __launch_bounds__(64) void fin_kernel(
    const float* __restrict__ ll, const float* __restrict__ msum,
    float* __restrict__ outF)
{
    const int lane = threadIdx.x;
    float l = ll[lane];
    float m = msum[lane];
    #pragma unroll
    for (int off = 32; off >= 1; off >>= 1) {
        l += __shfl_xor(l, off, 64);
        m += __shfl_xor(m, off, 64);
    }
    if (lane == 0) outF[0] = -l / m;
}

// ---------------- Fallback (ws too small): sequential CRF ----------------------
__global__ __launch_bounds__(64) void crf_kernel(
    const float* __restrict__ outF,
    const int*   __restrict__ tags,
    const int*   __restrict__ mask,
    const float* __restrict__ trans,
    const float* __restrict__ startT,
    const float* __restrict__ endT,
    float* __restrict__ ws)
{
    __shared__ float se[T_ * K_];
    __shared__ float sm[T_];
    __shared__ int   st[T_];
    const int b = blockIdx.x;
    const int lane = threadIdx.x;

    const float* lg = outF + 1 + (size_t)b * T_ * K_;
    for (int i = lane; i < T_ * K_; i += 64) se[i] = lg[i];
    for (int t = lane; t < T_; t += 64) {
        sm[t] = (float)mask[b * T_ + t];
        st[t] = tags[b * T_ + t];
    }
    __syncthreads();

    const int jc = lane < K_ ? lane : K_ - 1;
    float ET[K_];
    #pragma unroll
    for (int i = 0; i < K_; ++i) ET[i] = __expf(trans[i * K_ + jc]);

    float a0   = startT[jc] + se[jc];
    float r0   = __shfl(a0, 0, 64);
    float aRel = a0 - r0;
    float C    = r0;

    for (int t = 1; t < T_; ++t) {
        if (sm[t] != 0.0f) {
            float e = __expf(aRel);
            float s = 0.0f;
            #pragma unroll
            for (int i = 0; i < K_; ++i)
                s = fmaf(__shfl(e, i, 64), ET[i], s);
            float raw = __logf(s) + se[t * K_ + jc];
            float rr  = __shfl(raw, 0, 64);
            aRel = raw - rr;
            C   += rr;
        }
    }

    float contrib = (lane < K_) ? __expf(aRel + endT[jc]) : 0.0f;
    #pragma unroll
    for (int off = 32; off >= 1; off >>= 1) contrib += __shfl_xor(contrib, off, 64);
    const float logZ = C + __logf(contrib);

    float sc = 0.0f, ms = 0.0f;
    for (int t = lane; t < T_; t += 64) {
        const float mt = sm[t];
        ms += mt;
        if (t < T_ - 1) {
            const int ct = st[t], nt2 = st[t + 1];
            sc += trans[ct * K_ + nt2] * sm[t + 1] + se[t * K_ + ct] * mt;
        }
    }
    #pragma unroll
    for (int off = 32; off >= 1; off >>= 1) {
        sc += __shfl_xor(sc, off, 64);
        ms += __shfl_xor(ms, off, 64);
    }
    if (lane == 0) {
        const int lastIdx = (int)ms - 1;
        const int lastTag = st[lastIdx];
        sc += startT[st[0]] + endT[lastTag] + se[(T_ - 1) * K_ + lastTag] * sm[T_ - 1];
        ws[b]      = sc - logZ;
        ws[B_ + b] = ms;
    }
}

extern "C" void kernel_launch(void* const* d_in, const int* in_sizes, int n_in,
                              void* d_out, int out_size, void* d_ws, size_t ws_size,
                              hipStream_t stream) {
    const float* A     = (const float*)d_in[0];   // vectors [64,512,768] f32
    const int*   tags  = (const int*)  d_in[1];   // targets [64,512] i32
    const int*   mask  = (const int*)  d_in[2];   // mask    [64,512] i32
    const float* W     = (const float*)d_in[3];   // W [21,768] f32
    const float* bias  = (const float*)d_in[4];   // b [21]
    const float* trans = (const float*)d_in[5];   // transitions [21,21]
    const float* stT   = (const float*)d_in[6];   // start_trans [21]
    const float* enT   = (const float*)d_in[7];   // end_trans [21]
    float* outF = (float*)d_out;
    float* ws   = (float*)d_ws;

    proj_kernel<<<512, 256, 0, stream>>>(A, W, bias, outF);

    // ws layout (floats): G[64*32*448] | SC[64*32] | ll[64] | ms[64]
    const size_t gFloats  = (size_t)B_ * NCHUNK * GSTRIDE;
    const size_t scOff    = gFloats;
    const size_t llOff    = gFloats + (size_t)B_ * NCHUNK;
    const size_t msOff    = llOff + B_;
    const size_t needBytes = (msOff + B_) * sizeof(float);

    if (ws_size >= needBytes) {
        float* G   = ws;
        float* SC  = ws + scOff;
        float* llp = ws + llOff;
        float* msv = ws + msOff;
        chunk_kernel<<<dim3(NCHUNK, B_), 64, 0, stream>>>(outF, mask, trans, G, SC);
        scan_kernel<<<B_, 256, 0, stream>>>(outF, tags, mask, trans, stT, enT, G, SC, llp, msv);
        fin_kernel<<<1, 64, 0, stream>>>(llp, msv, outF);
    } else {
        crf_kernel<<<B_, 64, 0, stream>>>(outF, tags, mask, trans, stT, enT, ws);
        fin_kernel<<<1, 64, 0, stream>>>(ws, ws + B_, outF);
    }
}